// Round 18
// baseline (26.092 us; speedup 1.0000x reference)
//
#include <hip/hip_runtime.h>

#define NSEQ 4096
#define DIM  256
#define WIN  128
#define BATCH 4

typedef __bf16 bf16x8 __attribute__((ext_vector_type(8)));
typedef float  f32x4  __attribute__((ext_vector_type(4)));
typedef int    v2i    __attribute__((ext_vector_type(2)));
typedef int    v4i    __attribute__((ext_vector_type(4)));

// subtiled layout: element (j,d) of a 32x256 tile at
// ((j>>2)*16 + (d>>4))*64 + (j&3)*16 + (d&15)  halfwords. (verified r2-r17)
__device__ __forceinline__ int sub_off(int j, int d) {
    return (((j >> 2) * 16 + (d >> 4)) << 6) + ((j & 3) << 4) + (d & 15);
}

__device__ __forceinline__ unsigned short f2bf(float f) {
    unsigned u = __builtin_bit_cast(unsigned, f);
    u += 0x7fffu + ((u >> 16) & 1u);   // RNE
    return (unsigned short)(u >> 16);
}

__device__ __forceinline__ unsigned pk2bf(float lo, float hi) {
    unsigned r;
    asm("v_cvt_pk_bf16_f32 %0, %1, %2" : "=v"(r) : "v"(lo), "v"(hi));
    return r;
}

// async global->LDS DMA, 16B/lane; dst wave-uniform, src per-lane (r13-verified)
__device__ __forceinline__ void gload16(const void* g, void* l) {
    __builtin_amdgcn_global_load_lds(
        (const __attribute__((address_space(1))) unsigned int*)g,
        (__attribute__((address_space(3))) unsigned int*)l, 16, 0, 0);
}

// ---- pre-pass: f32 -> bf16 subtiled tiles in ws (r13 verbatim, verified) ----
__global__ __launch_bounds__(256)
void cvt_kernel(const float* __restrict__ val, unsigned short* __restrict__ wsA) {
    __shared__ unsigned short A_l[8192];
    const int tile = blockIdx.x;
    const float* src = val + ((size_t)tile << 13);
    const int t = threadIdx.x;
    const int j = t >> 3;
    const int dbase = (t & 7) << 2;

    #pragma unroll
    for (int p = 0; p < 8; ++p) {
        const int d = dbase + (p << 5);
        float4 v = *reinterpret_cast<const float4*>(src + j * 256 + d);
        uint2 u;
        u.x = pk2bf(v.x, v.y);
        u.y = pk2bf(v.z, v.w);
        *reinterpret_cast<uint2*>(&A_l[sub_off(j, d)]) = u;
    }
    __syncthreads();
    unsigned short* dstA = wsA + ((size_t)tile << 13);
    #pragma unroll
    for (int i = 0; i < 4; ++i) {
        uint4 x = *reinterpret_cast<const uint4*>(&A_l[(i << 11) + (t << 3)]);
        *reinterpret_cast<uint4*>(dstA + (i << 11) + (t << 3)) = x;
    }
}

#define ESTR 40

// ---- main: BARRIER-FREE. Each wave owns a 16-row i-tile, private LDS, counted vmcnt ----
__global__ __launch_bounds__(256)
void sp_kernel(const unsigned short* __restrict__ wsA,
               const float* __restrict__ state,
               float* __restrict__ out) {
    __shared__ __align__(128) unsigned short V[4][2][8192];   // 128 KB: per-wave private dbuf
    __shared__ __align__(128) unsigned short Ebuf[4][16 * ESTR]; // 5 KB: per-wave private E

    // XCD swizzle (256 blocks = 8*32)
    const int bx  = blockIdx.x;
    const int lbx = ((bx & 7) << 5) + (bx >> 3);

    const int t   = threadIdx.x;
    const int w   = t >> 6;
    const int l   = t & 63;
    const int l15 = l & 15;
    const int l4  = l >> 4;

    const int unit   = lbx * 4 + w;          // 1024 independent 16-row units
    const int b      = unit >> 8;
    const int tile16 = unit & 255;
    const int i0     = tile16 << 4;

    const unsigned short* wsb = wsA + ((size_t)b << 20);   // b * 128 * 8192
    const float* stb  = state + ((size_t)b << 12);
    float* out_state  = out + ((size_t)b << 12);
    float* out_val    = out + (size_t)BATCH * NSEQ + (((size_t)b << 12) * DIM);

    unsigned short* v0 = &V[w][0][0];
    unsigned short* v1 = &V[w][1][0];
    unsigned short* Ew = &Ebuf[w][0];

    const int jb0   = (i0 >= WIN) ? ((i0 - WIN) & ~31) : 0;
    const int ntile = (((i0 & ~31) - jb0) >> 5) + 1;       // 1..5, wave-uniform
    const int tj0   = jb0 >> 5;                            // first 32-row tile index

    // ---- af: Vi rows i0..i0+15 direct from wsA (global bf16x8, 16B frags) ----
    const int ir = (i0 & 16) + l15;
    const unsigned short* wti = wsb + (((size_t)(i0 >> 5)) << 13);
    bf16x8 af[8];
    #pragma unroll
    for (int ks = 0; ks < 8; ++ks)
        af[ks] = *reinterpret_cast<const bf16x8*>(wti + sub_off(ir, (l4 << 3) + (ks << 5)));

    // ---- state preload (all frames) ----
    float st0[5], st1[5];
    #pragma unroll
    for (int q = 0; q < 5; ++q) {
        const int jj = jb0 + (q << 5);
        st0[q] = (q < ntile) ? stb[jj + l15] : 0.f;
        st1[q] = (q < ntile) ? stb[jj + 16 + l15] : 0.f;
    }

    // ---- prologue: DMA tile 0 into v0 ----
    {
        const char* g = (const char*)wsb + (((size_t)tj0) << 14) + (l << 4);
        #pragma unroll
        for (int k = 0; k < 16; ++k)
            gload16(g + (k << 10), ((char*)v0) + (k << 10));
    }

    float dsacc[4] = {0.f, 0.f, 0.f, 0.f};
    f32x4 accpv[16];
    #pragma unroll
    for (int nt = 0; nt < 16; ++nt)
        accpv[nt] = (f32x4){0.f, 0.f, 0.f, 0.f};

    #pragma unroll
    for (int q = 0; q < 5; ++q) {
        if (q >= ntile) break;
        unsigned short* cur = (q & 1) ? v1 : v0;
        unsigned short* nxt = (q & 1) ? v0 : v1;
        const int jb = jb0 + (q << 5);

        // ---- counted prefetch: issue next tile, then wait only for cur's 16 ----
        if (q + 1 < ntile) {
            const char* g = (const char*)wsb + (((size_t)(tj0 + q + 1)) << 14) + (l << 4);
            #pragma unroll
            for (int k = 0; k < 16; ++k)
                gload16(g + (k << 10), ((char*)nxt) + (k << 10));
            asm volatile("s_waitcnt vmcnt(16)" ::: "memory");
        } else {
            asm volatile("s_waitcnt vmcnt(0)" ::: "memory");
        }

        // ---- scores: 16 rows x 32 j, K=256; two n-tiles sequentially ----
        f32x4 acc[2];
        #pragma unroll
        for (int n = 0; n < 2; ++n) {
            acc[n] = (f32x4){0.f, 0.f, 0.f, 0.f};
            const int jc = (n << 4) + l15;
            bf16x8 sb[8];
            #pragma unroll
            for (int ks = 0; ks < 8; ++ks)
                sb[ks] = *reinterpret_cast<const bf16x8*>(&cur[sub_off(jc, (l4 << 3) + (ks << 5))]);
            #pragma unroll
            for (int ks = 0; ks < 8; ++ks)
                acc[n] = __builtin_amdgcn_mfma_f32_16x16x32_bf16(af[ks], sb[ks], acc[n], 0, 0, 0);
        }

        // ---- edges + dsacc + private E write (C: row=l4*4+r -> i, col=l15 -> j) ----
        #pragma unroll
        for (int r = 0; r < 4; ++r) {
            const int ig = i0 + (l4 << 2) + r;
            const int jg0 = jb + l15;
            float s0 = acc[0][r] * 0.0625f;
            float e0 = s0 * __builtin_amdgcn_rcpf(1.0f + fabsf(s0));
            if (jg0 > ig || jg0 < ig - WIN) e0 = 0.0f;
            const int jg1 = jg0 + 16;
            float s1 = acc[1][r] * 0.0625f;
            float e1 = s1 * __builtin_amdgcn_rcpf(1.0f + fabsf(s1));
            if (jg1 > ig || jg1 < ig - WIN) e1 = 0.0f;
            dsacc[r] += e0 * st0[q] + e1 * st1[q];
            Ew[((l4 << 2) + r) * ESTR + l15]      = f2bf(e0);
            Ew[((l4 << 2) + r) * ESTR + 16 + l15] = f2bf(e1);
        }

        // ---- PV A-frag from private E (intra-wave lgkmcnt orders write->read) ----
        bf16x8 pa = *reinterpret_cast<const bf16x8*>(&Ew[l15 * ESTR + (l4 << 3)]);

        // ---- PV: 16 d-subtiles, tr-reads in 4 groups of 8 ----
        const unsigned lds_base = (unsigned)(size_t)cur;
        #pragma unroll
        for (int g = 0; g < 4; ++g) {
            v2i tr[8];
            #pragma unroll
            for (int h = 0; h < 4; ++h) {
                const int nt = (g << 2) + h;
                unsigned a0 = lds_base + (unsigned)((((l4 << 5) + nt) << 7) + (l15 << 3));
                asm volatile("ds_read_b64_tr_b16 %0, %1" : "=v"(tr[2 * h]) : "v"(a0) : "memory");
                asm volatile("ds_read_b64_tr_b16 %0, %1 offset:2048" : "=v"(tr[2 * h + 1]) : "v"(a0) : "memory");
            }
            asm volatile("s_waitcnt lgkmcnt(0)" ::: "memory");
            __builtin_amdgcn_sched_barrier(0);
            #pragma unroll
            for (int h = 0; h < 4; ++h) {
                const int nt = (g << 2) + h;
                v4i tmp;
                tmp.x = tr[2 * h].x;     tmp.y = tr[2 * h].y;
                tmp.z = tr[2 * h + 1].x; tmp.w = tr[2 * h + 1].y;
                bf16x8 bfr = __builtin_bit_cast(bf16x8, tmp);
                accpv[nt] = __builtin_amdgcn_mfma_f32_16x16x32_bf16(pa, bfr, accpv[nt], 0, 0, 0);
            }
        }
    }

    // ---- delta_state: reduce over 16 j-lanes (l15); lanes l15==0 write 4 rows each ----
    #pragma unroll
    for (int m = 1; m <= 8; m <<= 1) {
        #pragma unroll
        for (int r = 0; r < 4; ++r)
            dsacc[r] += __shfl_xor(dsacc[r], m, 64);
    }
    if (l15 == 0) {
        #pragma unroll
        for (int r = 0; r < 4; ++r)
            out_state[i0 + (l4 << 2) + r] = dsacc[r];
    }

    // ---- delta_val epilogue: C row=l4*4+r (i), col=l15 (d within nt) ----
    #pragma unroll
    for (int nt = 0; nt < 16; ++nt) {
        const int d = (nt << 4) + l15;
        #pragma unroll
        for (int r = 0; r < 4; ++r) {
            const int ig = i0 + (l4 << 2) + r;
            out_val[(size_t)ig * DIM + d] = accpv[nt][r];
        }
    }
}

extern "C" void kernel_launch(void* const* d_in, const int* in_sizes, int n_in,
                              void* d_out, int out_size, void* d_ws, size_t ws_size,
                              hipStream_t stream) {
    const float* val   = (const float*)d_in[0];
    const float* state = (const float*)d_in[1];
    float* out = (float*)d_out;
    unsigned short* wsA = (unsigned short*)d_ws;   // 8.4 MB

    cvt_kernel<<<dim3(BATCH * 128), dim3(256), 0, stream>>>(val, wsA);
    sp_kernel<<<dim3(BATCH * 64), dim3(256), 0, stream>>>(wsA, state, out);
}